// Round 10
// baseline (105.558 us; speedup 1.0000x reference)
//
#include <hip/hip_runtime.h>
#include <cstdint>
#include <cstddef>

typedef __bf16 bf16;
typedef __bf16 bf16x8 __attribute__((ext_vector_type(8)));
typedef float  f32x4  __attribute__((ext_vector_type(4)));

#define MFMA16(a,b,c) __builtin_amdgcn_mfma_f32_16x16x32_bf16((a),(b),(c),0,0,0)

__device__ __forceinline__ void gload_lds16(const bf16* g, bf16* l) {
  __builtin_amdgcn_global_load_lds((__attribute__((address_space(1))) void*)(g),
                                   (__attribute__((address_space(3))) void*)(l),
                                   16, 0, 0);
}

// ---------------- fused prep: x-cast | E-cast | 4x weight transpose ----------------
__global__ __launch_bounds__(256) void prep_k(
    const float* __restrict__ x, const float* __restrict__ E,
    const float* __restrict__ W0, const float* __restrict__ W1,
    const float* __restrict__ W2, const float* __restrict__ W3,
    bf16* __restrict__ xb, bf16* __restrict__ Eb, bf16* __restrict__ Wt) {
  __shared__ float t[32][33];
  const int bid = blockIdx.x;
  const int tid = threadIdx.x;
  if (bid < 2176) {
    const bool isx = (bid < 2048);
    const float* src = isx ? x : E;
    bf16* dst = isx ? xb : Eb;
    const int n = isx ? (2048 * 1024) : (2047 * 64);
    const int i = (isx ? bid : (bid - 2048)) * 1024 + tid * 4;
    if (i < n) {
      float4 v = *(const float4*)(src + i);
      dst[i + 0] = (bf16)v.x;
      dst[i + 1] = (bf16)v.y;
      dst[i + 2] = (bf16)v.z;
      dst[i + 3] = (bf16)v.w;
    }
  } else {
    const int tt = bid - 2176;          // 0..4095
    const int z = tt >> 10;
    const int rem = tt & 1023;
    const int cx = (rem & 31) * 32;
    const int ry = (rem >> 5) * 32;
    const float* src = (z == 0) ? W0 : (z == 1) ? W1 : (z == 2) ? W2 : W3;
    bf16* dst = Wt + (size_t)z * (1024 * 1024);
    const int xx = tid & 31, yy = tid >> 5;
    #pragma unroll
    for (int j = 0; j < 32; j += 8) t[yy + j][xx] = src[(size_t)(ry + yy + j) * 1024 + cx + xx];
    __syncthreads();
    #pragma unroll
    for (int j = 0; j < 32; j += 8)
      dst[(size_t)(cx + yy + j) * 1024 + ry + xx] = (bf16)t[xx][yy + j];
  }
}

// ------- (2*RM*16) x 128 tile bf16 GEMM, 512 thr / 8 waves, BK=64 dbuf, swizzled -------
template <int RM, int RN>
__global__ __launch_bounds__(512, 4) void gemm512(
    const bf16* __restrict__ A, const bf16* __restrict__ Bt,
    bf16* __restrict__ QKV) {
  constexpr int K = 1024;
  constexpr int MT = 2 * RM * 16;
  const int row0 = blockIdx.x * MT;
  const int col0 = blockIdx.y * 128;

  __shared__ bf16 As[2][MT * 64];
  __shared__ bf16 Bs[2][128 * 64];

  const int tid = threadIdx.x;
  const int lane = tid & 63;
  const int wid = tid >> 6;            // 0..7
  const int wr = wid >> 2, wc = wid & 3;
  const int lr = lane & 15;
  const int g  = lane >> 4;
  const int srow8 = lane >> 3;
  const int scol = ((lane & 7) ^ srow8) * 8;

  f32x4 acc[RM][RN];
  #pragma unroll
  for (int a = 0; a < RM; ++a)
    #pragma unroll
    for (int b = 0; b < RN; ++b) acc[a][b] = (f32x4){0.f, 0.f, 0.f, 0.f};

  auto stg = [&](int bb, int k0_) {
    constexpr int ARW = MT / 8;
    #pragma unroll
    for (int q = 0; q < ARW / 8; ++q)
      gload_lds16(A + (size_t)(row0 + wid * ARW + q * 8 + srow8) * K + k0_ + scol,
                  &As[bb][(wid * ARW + q * 8) * 64]);
    #pragma unroll
    for (int q = 0; q < 2; ++q)
      gload_lds16(Bt + (size_t)(col0 + wid * 16 + q * 8 + srow8) * K + k0_ + scol,
                  &Bs[bb][(wid * 16 + q * 8) * 64]);
  };

  stg(0, 0);
  for (int t = 0; t < K / 64; ++t) {
    __syncthreads();
    if (t + 1 < K / 64) stg((t + 1) & 1, (t + 1) * 64);
    const bf16* as = &As[t & 1][0];
    const bf16* bs = &Bs[t & 1][0];
    bf16x8 af[RM][2], bfv[RN][2];
    #pragma unroll
    for (int mi = 0; mi < RM; ++mi)
      #pragma unroll
      for (int kk = 0; kk < 2; ++kk)
        af[mi][kk] = *(const bf16x8*)&as[(wr * RM * 16 + mi * 16 + lr) * 64 +
                                         ((kk * 32 + g * 8) ^ ((lr & 7) << 3))];
    #pragma unroll
    for (int ni = 0; ni < RN; ++ni)
      #pragma unroll
      for (int kk = 0; kk < 2; ++kk)
        bfv[ni][kk] = *(const bf16x8*)&bs[(wc * RN * 16 + ni * 16 + lr) * 64 +
                                          ((kk * 32 + g * 8) ^ ((lr & 7) << 3))];
    #pragma unroll
    for (int mi = 0; mi < RM; ++mi)
      #pragma unroll
      for (int ni = 0; ni < RN; ++ni)
        #pragma unroll
        for (int kk = 0; kk < 2; ++kk)
          acc[mi][ni] = MFMA16(af[mi][kk], bfv[ni][kk], acc[mi][ni]);
  }

  // QKV epilogue: col>>10 selects Q/K/V region; V written transposed
  #pragma unroll
  for (int mi = 0; mi < RM; ++mi) {
    #pragma unroll
    for (int ni = 0; ni < RN; ++ni) {
      #pragma unroll
      for (int r = 0; r < 4; ++r) {
        const int row = row0 + wr * RM * 16 + mi * 16 + g * 4 + r;
        const int col = col0 + wc * RN * 16 + ni * 16 + lr;
        const float v = acc[mi][ni][r];
        const int b = row >> 10, i = row & 1023;
        const int which = col >> 10, cc = col & 1023;
        const int h = cc >> 6, d = cc & 63;
        if (which < 2)
          QKV[(size_t)which * 2097152 + (((size_t)(b * 16 + h)) * 1024 + i) * 64 + d] = (bf16)v;
        else
          QKV[(size_t)2 * 2097152 + (((size_t)(b * 16 + h)) * 64 + d) * 1024 + i] = (bf16)v;
      }
    }
  }
}

// ---------------- causal flash attention: barrier-minimal, 8-wave blocks ----------------
__device__ const int CH_QB[36] = {7,7,7,7,7,7,7, 6,6,6,6,6,6, 5,5,5,5,5, 4,4,4,4,
                                  3,3,3, 2,2, 1, 0,1,2,3,4,5,6,7};
__device__ const int CH_K0[36] = {0,2,4,6,8,10,12, 0,2,4,6,8,10, 0,2,4,6,8, 0,2,4,6,
                                  0,2,4, 0,2, 0, 0,2,4,6,8,10,12,14};
__device__ const int QB_P0[8] = {0,1,3,6,10,15,21,28};

__global__ __launch_bounds__(512, 4) void attn_kernel(
    const bf16* __restrict__ Qh, const bf16* __restrict__ Kh,
    const bf16* __restrict__ Vt, const bf16* __restrict__ Eb,
    bf16* __restrict__ OP, float* __restrict__ LP) {
  constexpr int N = 1024;
  const int flat = blockIdx.y * 36 + blockIdx.x;
  const int task = (flat & 7) * 144 + (flat >> 3);
  const int bh = task / 36;
  const int ch = task - bh * 36;
  const int qb = CH_QB[ch];
  const int kb0 = CH_K0[ch];
  const int i0 = qb * 128;

  const bf16* Qp = Qh + (size_t)bh * N * 64;
  const bf16* Kp = Kh + (size_t)bh * N * 64;
  const bf16* Vp = Vt + (size_t)bh * 64 * N;

  __shared__ bf16 Ks[2][64 * 64];
  __shared__ bf16 Vs[2][64 * 64];
  __shared__ bf16 Es[256 * 64];
  __shared__ bf16 Psm[8][16 * 64];

  const int tid = threadIdx.x;
  const int lane = tid & 63;
  const int wid = tid >> 6;
  const int lr = lane & 15;
  const int g  = lane >> 4;
  const int iw0 = i0 + wid * 16;
  bf16* pp = &Psm[wid][0];

  const int srow8 = lane >> 3;
  const int sch = ((lane & 7) ^ srow8) * 8;

  bf16x8 qf[2];
  {
    const bf16* qrow = Qp + (size_t)(iw0 + lr) * 64 + g * 8;
    qf[0] = *(const bf16x8*)(qrow);
    qf[1] = *(const bf16x8*)(qrow + 32);
  }

  float lb[4] = {0.f, 0.f, 0.f, 0.f};
  f32x4 oacc[4];
  #pragma unroll
  for (int r = 0; r < 4; ++r) oacc[r] = (f32x4){0.f, 0.f, 0.f, 0.f};

  constexpr float SC = 0.18033688f;    // 0.125 * log2(e)
  const int fb = 7 - wid;
  const int j0a = kb0 * 64;
  const int ebase0 = (N - 128) + j0a - i0;

  auto STAGE_KV = [&](int b, int j0) {
    gload_lds16(Kp + (size_t)(j0 + wid * 8 + srow8) * 64 + sch, &Ks[b][(wid * 8) * 64]);
    gload_lds16(Vp + (size_t)(wid * 8 + srow8) * 1024 + j0 + sch, &Vs[b][(wid * 8) * 64]);
  };
  auto STAGE_E = [&]() {
    #pragma unroll
    for (int q = 0; q < 4; ++q)
      gload_lds16(Eb + (size_t)(ebase0 + wid * 32 + q * 8 + srow8) * 64 + sch,
                  &Es[(wid * 32 + q * 8) * 64]);
  };

  auto TILE = [&](int buf, int j0, int eoff) {
    if (j0 > iw0 + 15) return;
    const bf16* kbuf = &Ks[buf][0];
    const bf16* vbuf = &Vs[buf][0];
    f32x4 sa[4];
    #pragma unroll
    for (int ni = 0; ni < 4; ++ni) sa[ni] = (f32x4){0.f, 0.f, 0.f, 0.f};
    __builtin_amdgcn_s_setprio(1);
    #pragma unroll
    for (int ni = 0; ni < 4; ++ni)
      #pragma unroll
      for (int kk = 0; kk < 2; ++kk) {
        bf16x8 kf = *(const bf16x8*)&kbuf[(ni * 16 + lr) * 64 +
                                          ((kk * 32 + g * 8) ^ ((lr & 7) << 3))];
        sa[ni] = MFMA16(qf[kk], kf, sa[ni]);
      }
    f32x4 ea[5];
    #pragma unroll
    for (int s5 = 0; s5 < 5; ++s5) {
      const int er = eoff + (fb + s5) * 16 + lr;
      ea[s5] = (f32x4){0.f, 0.f, 0.f, 0.f};
      bf16x8 e0 = *(const bf16x8*)&Es[er * 64 + ((g * 8) ^ ((lr & 7) << 3))];
      bf16x8 e1 = *(const bf16x8*)&Es[er * 64 + ((32 + g * 8) ^ ((lr & 7) << 3))];
      ea[s5] = MFMA16(qf[0], e0, ea[s5]);
      ea[s5] = MFMA16(qf[1], e1, ea[s5]);
    }
    __builtin_amdgcn_s_setprio(0);
    #pragma unroll
    for (int r = 0; r < 4; ++r) {
      const int di = g * 4 + r;
      const int sl = (g << 4) | ((lr - di - 1) & 15);
      const float sh0 = __shfl(ea[0][r], sl);
      const float sh1 = __shfl(ea[1][r], sl);
      const float sh2 = __shfl(ea[2][r], sl);
      const float sh3 = __shfl(ea[3][r], sl);
      const float sh4 = __shfl(ea[4][r], sl);
      const bool hi = (lr > di);
      const float rel[4] = {hi ? sh1 : sh0, hi ? sh2 : sh1, hi ? sh3 : sh2, hi ? sh4 : sh3};
      const int ig = iw0 + di;
      #pragma unroll
      for (int ni = 0; ni < 4; ++ni) {
        float tv = (sa[ni][r] + rel[ni]) * SC;
        tv = (j0 + ni * 16 + lr > ig) ? -1e30f : tv;
        const float pv = exp2f(tv);
        lb[r] += pv;
        pp[di * 64 + ((ni * 16 + lr) ^ ((di & 7) << 3))] = (bf16)pv;
      }
    }
    bf16x8 pf[2];
    pf[0] = *(const bf16x8*)&pp[lr * 64 + ((g * 8) ^ ((lr & 7) << 3))];
    pf[1] = *(const bf16x8*)&pp[lr * 64 + ((32 + g * 8) ^ ((lr & 7) << 3))];
    __builtin_amdgcn_s_setprio(1);
    #pragma unroll
    for (int nd = 0; nd < 4; ++nd)
      #pragma unroll
      for (int kk = 0; kk < 2; ++kk) {
        bf16x8 vf = *(const bf16x8*)&vbuf[(nd * 16 + lr) * 64 +
                                          ((kk * 32 + g * 8) ^ ((lr & 7) << 3))];
        oacc[nd] = MFMA16(pf[kk], vf, oacc[nd]);
      }
    __builtin_amdgcn_s_setprio(0);
  };

  STAGE_E();
  STAGE_KV(0, j0a);
  __syncthreads();
  STAGE_KV(1, j0a + 64);
  TILE(0, j0a, 0);
  __syncthreads();
  TILE(1, j0a + 64, 64);

  #pragma unroll
  for (int off = 1; off < 16; off <<= 1)
    #pragma unroll
    for (int r = 0; r < 4; ++r)
      lb[r] += __shfl_xor(lb[r], off);

  const int pslot = bh * 36 + QB_P0[qb] + (kb0 >> 1);
  bf16* Op = OP + (size_t)pslot * 8192;
  #pragma unroll
  for (int nd = 0; nd < 4; ++nd)
    #pragma unroll
    for (int r = 0; r < 4; ++r)
      Op[(size_t)(wid * 16 + g * 4 + r) * 64 + nd * 16 + lr] = (bf16)oacc[nd][r];
  if (lr == 0) {
    #pragma unroll
    for (int r = 0; r < 4; ++r)
      LP[pslot * 128 + wid * 16 + g * 4 + r] = lb[r];
  }
}

// ------- output projection with FUSED partial-merge A-staging -------
// C[2048,1024] = merge(OP,LP) @ Wot^T + bias. MT=64 (one qb per tile), BK=64
// (one head per K-step). A staged reg->LDS: sum np partials, scale by 1/sum(l).
__global__ __launch_bounds__(512, 2) void outproj_k(
    const bf16* __restrict__ OP, const float* __restrict__ LP,
    const bf16* __restrict__ Bt, float* __restrict__ Of,
    const float* __restrict__ bias) {
  constexpr int K = 1024;
  const int row0 = blockIdx.x * 64;
  const int col0 = blockIdx.y * 128;

  __shared__ bf16 As[2][64 * 64];
  __shared__ bf16 Bs[2][128 * 64];

  const int tid = threadIdx.x;
  const int lane = tid & 63;
  const int wid = tid >> 6;
  const int wr = wid >> 2, wc = wid & 3;
  const int lr = lane & 15;
  const int g  = lane >> 4;
  const int srow8 = lane >> 3;
  const int scol = ((lane & 7) ^ srow8) * 8;

  // fixed A-merge coordinates for this thread
  const int ar = wid * 8 + srow8;          // A-tile row 0..63
  const int gr = row0 + ar;
  const int b  = gr >> 10;
  const int i  = gr & 1023;
  const int qb = i >> 7;                   // uniform across block
  const int lrow = i & 127;
  const int np = qb + 1;
  const int p0base = QB_P0[qb];
  const int d0 = scol;                     // source col chunk (pre-swizzled)
  bf16* adst[2] = {&As[0][ar * 64 + (lane & 7) * 8], &As[1][ar * 64 + (lane & 7) * 8]};

  float av[8];
  float lsum;
  auto ldA = [&](int t) {                  // issue merge loads for K-step t (head h = t)
    const int p0 = (b * 16 + t) * 36 + p0base;
    lsum = 0.f;
    #pragma unroll
    for (int j = 0; j < 8; ++j) av[j] = 0.f;
    for (int c = 0; c < np; ++c) {
      lsum += LP[(p0 + c) * 128 + lrow];
      const bf16x8 v = *(const bf16x8*)&OP[(size_t)(p0 + c) * 8192 + lrow * 64 + d0];
      #pragma unroll
      for (int j = 0; j < 8; ++j) av[j] += (float)v[j];
    }
  };
  auto wA = [&](int bb) {                  // normalize + write swizzled bf16 tile
    const float inv = 1.f / lsum;
    bf16x8 o;
    #pragma unroll
    for (int j = 0; j < 8; ++j) o[j] = (bf16)(av[j] * inv);
    *(bf16x8*)adst[bb] = o;
  };
  auto gB = [&](int bb, int k0_) {
    #pragma unroll
    for (int q = 0; q < 2; ++q)
      gload_lds16(Bt + (size_t)(col0 + wid * 16 + q * 8 + srow8) * K + k0_ + scol,
                  &Bs[bb][(wid * 16 + q * 8) * 64]);
  };

  f32x4 acc[2][2];
  #pragma unroll
  for (int a = 0; a < 2; ++a)
    #pragma unroll
    for (int bb = 0; bb < 2; ++bb) acc[a][bb] = (f32x4){0.f, 0.f, 0.f, 0.f};

  ldA(0);
  gB(0, 0);
  wA(0);
  for (int t = 0; t < 16; ++t) {
    __syncthreads();                       // buf[t&1] ready (vmcnt+lgkm drained)
    if (t + 1 < 16) { ldA(t + 1); gB((t + 1) & 1, (t + 1) * 64); }
    const bf16* as = &As[t & 1][0];
    const bf16* bs = &Bs[t & 1][0];
    bf16x8 af[2][2], bfv[2][2];
    #pragma unroll
    for (int mi = 0; mi < 2; ++mi)
      #pragma unroll
      for (int kk = 0; kk < 2; ++kk)
        af[mi][kk] = *(const bf16x8*)&as[(wr * 32 + mi * 16 + lr) * 64 +
                                         ((kk * 32 + g * 8) ^ ((lr & 7) << 3))];
    #pragma unroll
    for (int ni = 0; ni < 2; ++ni)
      #pragma unroll
      for (int kk = 0; kk < 2; ++kk)
        bfv[ni][kk] = *(const bf16x8*)&bs[(wc * 32 + ni * 16 + lr) * 64 +
                                          ((kk * 32 + g * 8) ^ ((lr & 7) << 3))];
    #pragma unroll
    for (int mi = 0; mi < 2; ++mi)
      #pragma unroll
      for (int ni = 0; ni < 2; ++ni)
        #pragma unroll
        for (int kk = 0; kk < 2; ++kk)
          acc[mi][ni] = MFMA16(af[mi][kk], bfv[ni][kk], acc[mi][ni]);
    if (t + 1 < 16) wA((t + 1) & 1);       // write next A tile (reads of it crossed barrier)
  }

  #pragma unroll
  for (int mi = 0; mi < 2; ++mi)
    #pragma unroll
    for (int ni = 0; ni < 2; ++ni)
      #pragma unroll
      for (int r = 0; r < 4; ++r) {
        const int row = row0 + wr * 32 + mi * 16 + g * 4 + r;
        const int col = col0 + wc * 32 + ni * 16 + lr;
        Of[(size_t)row * 1024 + col] = acc[mi][ni][r] + bias[col];
      }
}

// ---------------- launch ----------------
extern "C" void kernel_launch(void* const* d_in, const int* in_sizes, int n_in,
                              void* d_out, int out_size, void* d_ws, size_t ws_size,
                              hipStream_t stream) {
  const float* x  = (const float*)d_in[0];
  const float* E  = (const float*)d_in[1];
  // d_in[2] = mask (causal by construction)
  const float* Wq = (const float*)d_in[3];
  const float* Wk = (const float*)d_in[4];
  const float* Wv = (const float*)d_in[5];
  const float* Wo = (const float*)d_in[6];
  const float* bo = (const float*)d_in[7];

  bf16* xb  = (bf16*)d_ws;               // 4 MiB
  bf16* Wqt = xb + 2048 * 1024;          // 8 MiB (Wq,Wk,Wv,Wo transposed, contiguous)
  bf16* Wot = Wqt + 3 * 1024 * 1024;
  bf16* Eb  = Wqt + 4 * 1024 * 1024;     // 256 KiB (rows 0..2046 valid)
  bf16* Qh  = Eb + 2048 * 64;            // 3 x 4 MiB (Q, K, V^T)
  bf16* OPb = Qh + 3 * 2048 * 1024;      // 1152 x 8192 bf16 = 18.9 MiB
  float* LPp = (float*)(OPb + (size_t)1152 * 8192);  // 576 KiB
  float* out = (float*)d_out;

  prep_k<<<dim3(6272), dim3(256), 0, stream>>>(x, E, Wq, Wk, Wv, Wo, xb, Eb, Wqt);

  // fused QKV projection: [2048,1024] @ [3072,1024]^T, 128x128 tiles
  gemm512<4, 2><<<dim3(16, 24), dim3(512), 0, stream>>>(xb, Wqt, Qh);

  attn_kernel<<<dim3(36, 32), dim3(512), 0, stream>>>(
      Qh, Qh + 2048 * 1024, Qh + 2 * 2048 * 1024, Eb, OPb, LPp);

  // output projection with fused partial-merge
  outproj_k<<<dim3(32, 8), dim3(512), 0, stream>>>(OPb, LPp, Wot, out, bo);
}

// Round 11
// 83.203 us; speedup vs baseline: 1.2687x; 1.2687x over previous
//
#include <hip/hip_runtime.h>
#include <cstdint>
#include <cstddef>

typedef __bf16 bf16;
typedef __bf16 bf16x8 __attribute__((ext_vector_type(8)));
typedef float  f32x4  __attribute__((ext_vector_type(4)));

#define MFMA16(a,b,c) __builtin_amdgcn_mfma_f32_16x16x32_bf16((a),(b),(c),0,0,0)

__device__ __forceinline__ void gload_lds16(const bf16* g, bf16* l) {
  __builtin_amdgcn_global_load_lds((__attribute__((address_space(1))) void*)(g),
                                   (__attribute__((address_space(3))) void*)(l),
                                   16, 0, 0);
}

// ---------------- fused prep: x-cast | E-cast | 4x weight transpose ----------------
__global__ __launch_bounds__(256) void prep_k(
    const float* __restrict__ x, const float* __restrict__ E,
    const float* __restrict__ W0, const float* __restrict__ W1,
    const float* __restrict__ W2, const float* __restrict__ W3,
    bf16* __restrict__ xb, bf16* __restrict__ Eb, bf16* __restrict__ Wt) {
  __shared__ float t[32][33];
  const int bid = blockIdx.x;
  const int tid = threadIdx.x;
  if (bid < 2176) {
    const bool isx = (bid < 2048);
    const float* src = isx ? x : E;
    bf16* dst = isx ? xb : Eb;
    const int n = isx ? (2048 * 1024) : (2047 * 64);
    const int i = (isx ? bid : (bid - 2048)) * 1024 + tid * 4;
    if (i < n) {
      float4 v = *(const float4*)(src + i);
      dst[i + 0] = (bf16)v.x;
      dst[i + 1] = (bf16)v.y;
      dst[i + 2] = (bf16)v.z;
      dst[i + 3] = (bf16)v.w;
    }
  } else {
    const int tt = bid - 2176;          // 0..4095
    const int z = tt >> 10;
    const int rem = tt & 1023;
    const int cx = (rem & 31) * 32;
    const int ry = (rem >> 5) * 32;
    const float* src = (z == 0) ? W0 : (z == 1) ? W1 : (z == 2) ? W2 : W3;
    bf16* dst = Wt + (size_t)z * (1024 * 1024);
    const int xx = tid & 31, yy = tid >> 5;
    #pragma unroll
    for (int j = 0; j < 32; j += 8) t[yy + j][xx] = src[(size_t)(ry + yy + j) * 1024 + cx + xx];
    __syncthreads();
    #pragma unroll
    for (int j = 0; j < 32; j += 8)
      dst[(size_t)(cx + yy + j) * 1024 + ry + xx] = (bf16)t[xx][yy + j];
  }
}

// ------- (2*RM*16) x 128 tile bf16 GEMM, 512 thr / 8 waves, BK=64 dbuf, swizzled -------
// wave grid 2 x 4; per-wave RM*16 rows x RN*16 cols. mode 0: QKV epilogue; 2: fp32+bias.
template <int RM, int RN>
__global__ __launch_bounds__(512, 4) void gemm512(
    const bf16* __restrict__ A, const bf16* __restrict__ Bt,
    bf16* __restrict__ QKV, float* __restrict__ Of,
    const float* __restrict__ bias, const int mode) {
  constexpr int K = 1024;
  constexpr int MT = 2 * RM * 16;
  constexpr int NT = 4 * RN * 16;      // 128
  const int row0 = blockIdx.x * MT;
  const int col0 = blockIdx.y * NT;

  __shared__ bf16 As[2][MT * 64];
  __shared__ bf16 Bs[2][NT * 64];

  const int tid = threadIdx.x;
  const int lane = tid & 63;
  const int wid = tid >> 6;            // 0..7
  const int wr = wid >> 2, wc = wid & 3;
  const int lr = lane & 15;
  const int g  = lane >> 4;
  const int srow8 = lane >> 3;
  const int scol = ((lane & 7) ^ srow8) * 8;

  f32x4 acc[RM][RN];
  #pragma unroll
  for (int a = 0; a < RM; ++a)
    #pragma unroll
    for (int b = 0; b < RN; ++b) acc[a][b] = (f32x4){0.f, 0.f, 0.f, 0.f};

  auto stg = [&](int bb, int k0_) {
    constexpr int ARW = MT / 8;        // A rows per wave (16 or 8)
    #pragma unroll
    for (int q = 0; q < ARW / 8; ++q)
      gload_lds16(A + (size_t)(row0 + wid * ARW + q * 8 + srow8) * K + k0_ + scol,
                  &As[bb][(wid * ARW + q * 8) * 64]);
    #pragma unroll
    for (int q = 0; q < 2; ++q)
      gload_lds16(Bt + (size_t)(col0 + wid * 16 + q * 8 + srow8) * K + k0_ + scol,
                  &Bs[bb][(wid * 16 + q * 8) * 64]);
  };

  stg(0, 0);
  for (int t = 0; t < K / 64; ++t) {
    __syncthreads();
    if (t + 1 < K / 64) stg((t + 1) & 1, (t + 1) * 64);
    const bf16* as = &As[t & 1][0];
    const bf16* bs = &Bs[t & 1][0];
    bf16x8 af[RM][2], bfv[RN][2];
    #pragma unroll
    for (int mi = 0; mi < RM; ++mi)
      #pragma unroll
      for (int kk = 0; kk < 2; ++kk)
        af[mi][kk] = *(const bf16x8*)&as[(wr * RM * 16 + mi * 16 + lr) * 64 +
                                         ((kk * 32 + g * 8) ^ ((lr & 7) << 3))];
    #pragma unroll
    for (int ni = 0; ni < RN; ++ni)
      #pragma unroll
      for (int kk = 0; kk < 2; ++kk)
        bfv[ni][kk] = *(const bf16x8*)&bs[(wc * RN * 16 + ni * 16 + lr) * 64 +
                                          ((kk * 32 + g * 8) ^ ((lr & 7) << 3))];
    #pragma unroll
    for (int mi = 0; mi < RM; ++mi)
      #pragma unroll
      for (int ni = 0; ni < RN; ++ni)
        #pragma unroll
        for (int kk = 0; kk < 2; ++kk)
          acc[mi][ni] = MFMA16(af[mi][kk], bfv[ni][kk], acc[mi][ni]);
  }

  #pragma unroll
  for (int mi = 0; mi < RM; ++mi) {
    #pragma unroll
    for (int ni = 0; ni < RN; ++ni) {
      #pragma unroll
      for (int r = 0; r < 4; ++r) {
        const int row = row0 + wr * RM * 16 + mi * 16 + g * 4 + r;
        const int col = col0 + wc * RN * 16 + ni * 16 + lr;
        const float v = acc[mi][ni][r];
        if (mode == 2) {
          Of[(size_t)row * 1024 + col] = v + bias[col];
        } else {
          const int b = row >> 10, i = row & 1023;
          const int which = col >> 10, cc = col & 1023;
          const int h = cc >> 6, d = cc & 63;
          if (which < 2)
            QKV[(size_t)which * 2097152 + (((size_t)(b * 16 + h)) * 1024 + i) * 64 + d] = (bf16)v;
          else
            QKV[(size_t)2 * 2097152 + (((size_t)(b * 16 + h)) * 64 + d) * 1024 + i] = (bf16)v;
        }
      }
    }
  }
}

// ---------------- causal flash attention: single-barrier chunks, 8-wave blocks ----------------
// Q-tile 128 rows, chunk = 2 key-tiles, 36 chunks/bh, 1152 blocks. LDS: K/V both
// tiles (2x8K each) + E once-per-chunk (256 rows, 32K) + private P (16K) = 80K.
// ONE barrier per chunk: stage(E,KV0,KV1) -> barrier -> TILE0 -> TILE1 (no mid
// barrier; compiler interleaves tile1 MFMA/ds_reads into tile0's softmax stalls).
__device__ const int CH_QB[36] = {7,7,7,7,7,7,7, 6,6,6,6,6,6, 5,5,5,5,5, 4,4,4,4,
                                  3,3,3, 2,2, 1, 0,1,2,3,4,5,6,7};
__device__ const int CH_K0[36] = {0,2,4,6,8,10,12, 0,2,4,6,8,10, 0,2,4,6,8, 0,2,4,6,
                                  0,2,4, 0,2, 0, 0,2,4,6,8,10,12,14};
__device__ const int QB_P0[8] = {0,1,3,6,10,15,21,28};

__global__ __launch_bounds__(512, 4) void attn_kernel(
    const bf16* __restrict__ Qh, const bf16* __restrict__ Kh,
    const bf16* __restrict__ Vt, const bf16* __restrict__ Eb,
    bf16* __restrict__ OP, float* __restrict__ LP) {
  constexpr int N = 1024;
  const int flat = blockIdx.y * 36 + blockIdx.x;
  const int task = (flat & 7) * 144 + (flat >> 3);
  const int bh = task / 36;
  const int ch = task - bh * 36;
  const int qb = CH_QB[ch];
  const int kb0 = CH_K0[ch];
  const int i0 = qb * 128;

  const bf16* Qp = Qh + (size_t)bh * N * 64;
  const bf16* Kp = Kh + (size_t)bh * N * 64;
  const bf16* Vp = Vt + (size_t)bh * 64 * N;

  __shared__ bf16 Ks[2][64 * 64];
  __shared__ bf16 Vs[2][64 * 64];
  __shared__ bf16 Es[256 * 64];
  __shared__ bf16 Psm[8][16 * 64];

  const int tid = threadIdx.x;
  const int lane = tid & 63;
  const int wid = tid >> 6;
  const int lr = lane & 15;
  const int g  = lane >> 4;
  const int iw0 = i0 + wid * 16;
  bf16* pp = &Psm[wid][0];

  const int srow8 = lane >> 3;
  const int sch = ((lane & 7) ^ srow8) * 8;

  bf16x8 qf[2];
  {
    const bf16* qrow = Qp + (size_t)(iw0 + lr) * 64 + g * 8;
    qf[0] = *(const bf16x8*)(qrow);
    qf[1] = *(const bf16x8*)(qrow + 32);
  }

  float lb[4] = {0.f, 0.f, 0.f, 0.f};
  f32x4 oacc[4];
  #pragma unroll
  for (int r = 0; r < 4; ++r) oacc[r] = (f32x4){0.f, 0.f, 0.f, 0.f};

  constexpr float SC = 0.18033688f;    // 0.125 * log2(e)
  const int fb = 7 - wid;
  const int j0a = kb0 * 64;
  const int ebase0 = (N - 128) + j0a - i0;

  auto STAGE_KV = [&](int b, int j0) {
    gload_lds16(Kp + (size_t)(j0 + wid * 8 + srow8) * 64 + sch, &Ks[b][(wid * 8) * 64]);
    gload_lds16(Vp + (size_t)(wid * 8 + srow8) * 1024 + j0 + sch, &Vs[b][(wid * 8) * 64]);
  };
  auto STAGE_E = [&]() {
    #pragma unroll
    for (int q = 0; q < 4; ++q)
      gload_lds16(Eb + (size_t)(ebase0 + wid * 32 + q * 8 + srow8) * 64 + sch,
                  &Es[(wid * 32 + q * 8) * 64]);
  };

  auto TILE = [&](int buf, int j0, int eoff) {
    if (j0 > iw0 + 15) return;         // wave-uniform skip (above diagonal)
    const bf16* kbuf = &Ks[buf][0];
    const bf16* vbuf = &Vs[buf][0];
    f32x4 sa[4];
    #pragma unroll
    for (int ni = 0; ni < 4; ++ni) sa[ni] = (f32x4){0.f, 0.f, 0.f, 0.f};
    __builtin_amdgcn_s_setprio(1);
    #pragma unroll
    for (int ni = 0; ni < 4; ++ni)
      #pragma unroll
      for (int kk = 0; kk < 2; ++kk) {
        bf16x8 kf = *(const bf16x8*)&kbuf[(ni * 16 + lr) * 64 +
                                          ((kk * 32 + g * 8) ^ ((lr & 7) << 3))];
        sa[ni] = MFMA16(qf[kk], kf, sa[ni]);
      }
    f32x4 ea[5];
    #pragma unroll
    for (int s5 = 0; s5 < 5; ++s5) {
      const int er = eoff + (fb + s5) * 16 + lr;
      ea[s5] = (f32x4){0.f, 0.f, 0.f, 0.f};
      bf16x8 e0 = *(const bf16x8*)&Es[er * 64 + ((g * 8) ^ ((lr & 7) << 3))];
      bf16x8 e1 = *(const bf16x8*)&Es[er * 64 + ((32 + g * 8) ^ ((lr & 7) << 3))];
      ea[s5] = MFMA16(qf[0], e0, ea[s5]);
      ea[s5] = MFMA16(qf[1], e1, ea[s5]);
    }
    __builtin_amdgcn_s_setprio(0);
    #pragma unroll
    for (int r = 0; r < 4; ++r) {
      const int di = g * 4 + r;
      const int sl = (g << 4) | ((lr - di - 1) & 15);
      const float sh0 = __shfl(ea[0][r], sl);
      const float sh1 = __shfl(ea[1][r], sl);
      const float sh2 = __shfl(ea[2][r], sl);
      const float sh3 = __shfl(ea[3][r], sl);
      const float sh4 = __shfl(ea[4][r], sl);
      const bool hi = (lr > di);
      const float rel[4] = {hi ? sh1 : sh0, hi ? sh2 : sh1, hi ? sh3 : sh2, hi ? sh4 : sh3};
      const int ig = iw0 + di;
      #pragma unroll
      for (int ni = 0; ni < 4; ++ni) {
        float tv = (sa[ni][r] + rel[ni]) * SC;
        tv = (j0 + ni * 16 + lr > ig) ? -1e30f : tv;
        const float pv = exp2f(tv);
        lb[r] += pv;
        pp[di * 64 + ((ni * 16 + lr) ^ ((di & 7) << 3))] = (bf16)pv;
      }
    }
    bf16x8 pf[2];
    pf[0] = *(const bf16x8*)&pp[lr * 64 + ((g * 8) ^ ((lr & 7) << 3))];
    pf[1] = *(const bf16x8*)&pp[lr * 64 + ((32 + g * 8) ^ ((lr & 7) << 3))];
    __builtin_amdgcn_s_setprio(1);
    #pragma unroll
    for (int nd = 0; nd < 4; ++nd)
      #pragma unroll
      for (int kk = 0; kk < 2; ++kk) {
        bf16x8 vf = *(const bf16x8*)&vbuf[(nd * 16 + lr) * 64 +
                                          ((kk * 32 + g * 8) ^ ((lr & 7) << 3))];
        oacc[nd] = MFMA16(pf[kk], vf, oacc[nd]);
      }
    __builtin_amdgcn_s_setprio(0);
  };

  // single-barrier chunk: stage everything, one rendezvous, then both tiles
  STAGE_E();
  STAGE_KV(0, j0a);
  STAGE_KV(1, j0a + 64);
  __syncthreads();                     // E + KV0 + KV1 staged (vmcnt drained)
  TILE(0, j0a, 0);
  TILE(1, j0a + 64, 64);

  #pragma unroll
  for (int off = 1; off < 16; off <<= 1)
    #pragma unroll
    for (int r = 0; r < 4; ++r)
      lb[r] += __shfl_xor(lb[r], off);

  const int pslot = bh * 36 + QB_P0[qb] + (kb0 >> 1);
  bf16* Op = OP + (size_t)pslot * 8192;
  #pragma unroll
  for (int nd = 0; nd < 4; ++nd)
    #pragma unroll
    for (int r = 0; r < 4; ++r)
      Op[(size_t)(wid * 16 + g * 4 + r) * 64 + nd * 16 + lr] = (bf16)oacc[nd][r];
  if (lr == 0) {
    #pragma unroll
    for (int r = 0; r < 4; ++r)
      LP[pslot * 128 + wid * 16 + g * 4 + r] = lb[r];
  }
}

// ---------------- merge split-K partials (simple sums, m==0) -> AO bf16 ----------------
__global__ __launch_bounds__(256) void merge_k(const bf16* __restrict__ OP,
                                               const float* __restrict__ LP,
                                               bf16* __restrict__ AO) {
  const int bh = blockIdx.x;
  const int qb = blockIdx.y;
  const int half = blockIdx.z;
  const int np = qb + 1;
  const int tid = threadIdx.x;
  const int row = half * 64 + (tid >> 2);
  const int c0 = (tid & 3) * 16;
  const int p0 = bh * 36 + QB_P0[qb];

  float o[16];
  #pragma unroll
  for (int j = 0; j < 16; ++j) o[j] = 0.f;
  float l = 0.f;
  for (int c = 0; c < np; ++c) {
    l += LP[(p0 + c) * 128 + row];
    const bf16* Oc = OP + (size_t)(p0 + c) * 8192 + row * 64 + c0;
    #pragma unroll
    for (int j = 0; j < 16; j += 8) {
      const bf16x8 v = *(const bf16x8*)&Oc[j];
      #pragma unroll
      for (int u = 0; u < 8; ++u) o[j + u] += (float)v[u];
    }
  }
  const float inv = 1.f / l;

  const int b = bh >> 4, h = bh & 15;
  bf16* dst = AO + ((size_t)(b * 1024) + qb * 128 + row) * 1024 + h * 64 + c0;
  #pragma unroll
  for (int j = 0; j < 16; ++j) dst[j] = (bf16)(o[j] * inv);
}

// ---------------- launch ----------------
extern "C" void kernel_launch(void* const* d_in, const int* in_sizes, int n_in,
                              void* d_out, int out_size, void* d_ws, size_t ws_size,
                              hipStream_t stream) {
  const float* x  = (const float*)d_in[0];
  const float* E  = (const float*)d_in[1];
  // d_in[2] = mask (causal by construction)
  const float* Wq = (const float*)d_in[3];
  const float* Wk = (const float*)d_in[4];
  const float* Wv = (const float*)d_in[5];
  const float* Wo = (const float*)d_in[6];
  const float* bo = (const float*)d_in[7];

  bf16* xb  = (bf16*)d_ws;               // 4 MiB
  bf16* Wqt = xb + 2048 * 1024;          // 8 MiB (Wq,Wk,Wv,Wo transposed, contiguous)
  bf16* Wot = Wqt + 3 * 1024 * 1024;
  bf16* Eb  = Wqt + 4 * 1024 * 1024;     // 256 KiB (rows 0..2046 valid)
  bf16* Qh  = Eb + 2048 * 64;            // 3 x 4 MiB (Q, K, V^T)
  bf16* AO  = Qh + 3 * 2048 * 1024;      // 4 MiB
  bf16* OPb = AO + 2048 * 1024;          // 1152 x 8192 bf16 = 18.9 MiB
  float* LPp = (float*)(OPb + (size_t)1152 * 8192);  // 576 KiB
  float* out = (float*)d_out;

  prep_k<<<dim3(6272), dim3(256), 0, stream>>>(x, E, Wq, Wk, Wv, Wo, xb, Eb, Wqt);

  // fused QKV projection: [2048,1024] @ [3072,1024]^T, 128x128 tiles
  gemm512<4, 2><<<dim3(16, 24), dim3(512), 0, stream>>>(xb, Wqt, Qh, nullptr, nullptr, 0);

  attn_kernel<<<dim3(36, 32), dim3(512), 0, stream>>>(
      Qh, Qh + 2048 * 1024, Qh + 2 * 2048 * 1024, Eb, OPb, LPp);

  merge_k<<<dim3(32, 8, 2), dim3(256), 0, stream>>>(OPb, LPp, AO);

  // output projection: fp32 + bias, 64x128 tiles, 8 waves
  gemm512<2, 2><<<dim3(32, 8), dim3(512), 0, stream>>>(AO, Wot, nullptr, out, bo, 2);
}